// Round 11
// baseline (660.317 us; speedup 1.0000x reference)
//
#include <hip/hip_runtime.h>
#include <hip/hip_fp16.h>
#include <math.h>

#define IN_DIM 256
#define HID 48
#define CLS 16
#define K_STEPS 10
#define ALPHA 0.1f

// ---------------- non-temporal access helpers ----------------

typedef int   v4i __attribute__((ext_vector_type(4)));
typedef float v4f __attribute__((ext_vector_type(4)));

__device__ __forceinline__ int4 ntload_i4(const int* p) {
    v4i v = __builtin_nontemporal_load((const v4i*)p);
    return make_int4(v.x, v.y, v.z, v.w);
}
__device__ __forceinline__ float4 ntload_f4(const float* p) {
    v4f v = __builtin_nontemporal_load((const v4f*)p);
    return make_float4(v.x, v.y, v.z, v.w);
}
__device__ __forceinline__ void ntstore_f4(float* p, float4 v) {
    v4f t; t.x = v.x; t.y = v.y; t.z = v.z; t.w = v.w;
    __builtin_nontemporal_store(t, (v4f*)p);
}
__device__ __forceinline__ void ntstore_u64(void* p, unsigned long long v) {
    __builtin_nontemporal_store(v, (unsigned long long*)p);
}

// ---------------- utility ----------------

__global__ void zero_int_kernel(int* __restrict__ p, int n) {
    int i = blockIdx.x * blockDim.x + threadIdx.x;
    if (i < n) p[i] = 0;
}

__global__ void hist_kernel(const int* __restrict__ dst, int* __restrict__ deg, int nE) {
    int i = blockIdx.x * blockDim.x + threadIdx.x;
    if (i < nE) atomicAdd(&deg[__builtin_nontemporal_load(dst + i)], 1);
}

__global__ void norm_kernel(const int* __restrict__ deg, float* __restrict__ nrm, int n) {
    int i = blockIdx.x * blockDim.x + threadIdx.x;
    if (i < n) nrm[i] = rsqrtf(fmaxf((float)deg[i], 1.0f));
}

// ---------------- exclusive scan over deg -> off, cursor ----------------

__global__ __launch_bounds__(256) void scan1_kernel(const int* __restrict__ deg,
                                                    int* __restrict__ bsum, int n) {
    __shared__ int ls[256];
    int t = threadIdx.x;
    int base = blockIdx.x * 1024 + t * 4;
    int s = 0;
    if (base + 3 < n) {
        int4 d = *(const int4*)(deg + base);
        s = d.x + d.y + d.z + d.w;
    } else {
        for (int i = 0; i < 4; i++) if (base + i < n) s += deg[base + i];
    }
    ls[t] = s; __syncthreads();
    for (int o = 128; o > 0; o >>= 1) {
        if (t < o) ls[t] += ls[t + o];
        __syncthreads();
    }
    if (t == 0) bsum[blockIdx.x] = ls[0];
}

__global__ void scan2_kernel(int* __restrict__ bsum, int* __restrict__ off, int nb, int n) {
    if (threadIdx.x == 0 && blockIdx.x == 0) {
        int run = 0;
        for (int i = 0; i < nb; i++) { int t = bsum[i]; bsum[i] = run; run += t; }
        off[n] = run;
    }
}

__global__ __launch_bounds__(256) void scan3_kernel(const int* __restrict__ deg,
                                                    const int* __restrict__ bsum,
                                                    int* __restrict__ off,
                                                    int* __restrict__ cursor, int n) {
    __shared__ int ts[256];
    int t = threadIdx.x;
    int base = blockIdx.x * 1024 + t * 4;
    int d0 = 0, d1 = 0, d2 = 0, d3 = 0;
    if (base + 3 < n) {
        int4 d = *(const int4*)(deg + base);
        d0 = d.x; d1 = d.y; d2 = d.z; d3 = d.w;
    } else {
        if (base     < n) d0 = deg[base];
        if (base + 1 < n) d1 = deg[base + 1];
        if (base + 2 < n) d2 = deg[base + 2];
        if (base + 3 < n) d3 = deg[base + 3];
    }
    int s = d0 + d1 + d2 + d3;
    ts[t] = s; __syncthreads();
    for (int o = 1; o < 256; o <<= 1) {
        int v = (t >= o) ? ts[t - o] : 0;
        __syncthreads();
        ts[t] += v;
        __syncthreads();
    }
    int ex = ts[t] - s + bsum[blockIdx.x];
    int p0 = ex, p1 = ex + d0, p2 = p1 + d1, p3 = p2 + d2;
    if (base     < n) { off[base]     = p0; cursor[base]     = p0; }
    if (base + 1 < n) { off[base + 1] = p1; cursor[base + 1] = p1; }
    if (base + 2 < n) { off[base + 2] = p2; cursor[base + 2] = p2; }
    if (base + 3 < n) { off[base + 3] = p3; cursor[base + 3] = p3; }
}

// ---------------- XCD-partitioned filtered CSR fill ----------------
// Streaming src/dst reads are non-temporal so the group's csrc lines stay
// resident in its XCD L2 until all 16 slots fill (write-combining).

__global__ __launch_bounds__(256) void fill8_kernel(
    const int* __restrict__ src, const int* __restrict__ dst,
    int* __restrict__ cursor, int* __restrict__ csrc, int nE, int nper)
{
    const int g  = blockIdx.x & 7;
    const int bi = blockIdx.x >> 3;
    const int nb = gridDim.x >> 3;
    const int lo = g * nper, hi = lo + nper;
    for (int i = bi * 256 + threadIdx.x; i < nE; i += nb * 256) {
        int d = __builtin_nontemporal_load(dst + i);
        if (d >= lo && d < hi) {
            int p = atomicAdd(&cursor[d], 1);
            csrc[p] = __builtin_nontemporal_load(src + i);
        }
    }
}

// ---------------- Wc = W2 @ W1 [16,256], bc = W2 @ b1 [16] ----------------

__global__ __launch_bounds__(256) void wc_kernel(
    const float* __restrict__ W1, const float* __restrict__ W2,
    const float* __restrict__ b1, float* __restrict__ Wc, float* __restrict__ bc)
{
    int c = blockIdx.x;
    int k = threadIdx.x;
    float acc = 0.0f;
    #pragma unroll
    for (int j = 0; j < HID; j++)
        acc = fmaf(W2[c * HID + j], W1[j * IN_DIM + k], acc);
    Wc[c * IN_DIM + k] = acc;
    if (k == 0) {
        float b = 0.0f;
        for (int j = 0; j < HID; j++) b = fmaf(W2[c * HID + j], b1[j], b);
        bc[c] = b;
    }
}

// ---------------- fused fc: z0 = X @ Wc^T + bc (f32); A = half(z0*nrm) ----------------

#define BM 128
#define BK 16
__global__ __launch_bounds__(256) void fcz_kernel(
    const float* __restrict__ X, const float* __restrict__ Wc,
    const float* __restrict__ bc, const float* __restrict__ nrm,
    float* __restrict__ z0, __half* __restrict__ A, int n)
{
    __shared__ float Xs[BK][BM + 1];
    __shared__ float Ws[BK][CLS];
    const int t = threadIdx.x;
    const int tx = t & 31;
    const int ty = t >> 5;
    const int mbase = blockIdx.x * BM;
    float acc[4][2] = {{0}};

    for (int k0 = 0; k0 < IN_DIM; k0 += BK) {
        #pragma unroll
        for (int c0 = 0; c0 < 2; c0++) {
            int c = t + c0 * 256;
            int m = c >> 2, kc = (c & 3) << 2;
            int gm = mbase + m;
            float4 xv = make_float4(0.f, 0.f, 0.f, 0.f);
            if (gm < n) xv = ntload_f4(X + (size_t)gm * IN_DIM + k0 + kc);
            Xs[kc + 0][m] = xv.x; Xs[kc + 1][m] = xv.y;
            Xs[kc + 2][m] = xv.z; Xs[kc + 3][m] = xv.w;
        }
        if (t < 64) {
            int j = t >> 2, kc = (t & 3) << 2;
            float4 wv = *(const float4*)(Wc + (size_t)j * IN_DIM + k0 + kc);
            Ws[kc + 0][j] = wv.x; Ws[kc + 1][j] = wv.y;
            Ws[kc + 2][j] = wv.z; Ws[kc + 3][j] = wv.w;
        }
        __syncthreads();
        #pragma unroll
        for (int k = 0; k < BK; k++) {
            float a[4], b[2];
            #pragma unroll
            for (int im = 0; im < 4; im++) a[im] = Xs[k][tx + 32 * im];
            #pragma unroll
            for (int jn = 0; jn < 2; jn++) b[jn] = Ws[k][ty * 2 + jn];
            #pragma unroll
            for (int im = 0; im < 4; im++)
                #pragma unroll
                for (int jn = 0; jn < 2; jn++)
                    acc[im][jn] = fmaf(a[im], b[jn], acc[im][jn]);
        }
        __syncthreads();
    }

    #pragma unroll
    for (int im = 0; im < 4; im++) {
        int m = mbase + tx + 32 * im;
        if (m < n) {
            float nv = nrm[m];
            float r0 = acc[im][0] + bc[ty * 2 + 0];
            float r1 = acc[im][1] + bc[ty * 2 + 1];
            size_t idx = (size_t)m * CLS + ty * 2;
            z0[idx] = r0;
            z0[idx + 1] = r1;
            ((__half2*)A)[(size_t)m * 8 + ty] = __floats2half2_rn(r0 * nv, r1 * nv);
        }
    }
}

// ---------------- pull gather + fused combine (D=16, half storage) ----------------
// 4 lanes/node, 8B row loads (cached - A is the hot L2-resident array).
// csrc/tele reads and all outputs are non-temporal (streaming, one-touch)
// so they don't evict A from the XCD L2s.

struct __align__(8) half4 { __half2 a, b; };

__device__ __forceinline__ void hacc(float4& acc, half4 w) {
    float2 lo = __half22float2(w.a);
    float2 hi = __half22float2(w.b);
    acc.x += lo.x; acc.y += lo.y; acc.z += hi.x; acc.w += hi.y;
}
__device__ __forceinline__ float eluf(float x) {
    return x > 0.0f ? x : expm1f(x);
}

template<int MODE>
__global__ __launch_bounds__(256) void gatherh_kernel(
    const int* __restrict__ off, const int* __restrict__ csrc,
    const half4* __restrict__ A, const float* __restrict__ tele,
    const float* __restrict__ nrm, const float4* __restrict__ b2v,
    half4* __restrict__ outp, float* __restrict__ x0out,
    float* __restrict__ outf, int n)
{
    const int v = blockIdx.x * 64 + threadIdx.y;
    if (v >= n) return;
    const int lane = threadIdx.x;        // 0..3

    const int s = off[v], e = off[v + 1];
    float4 a0 = make_float4(0.f, 0.f, 0.f, 0.f), a1 = a0;
    int i = s;
    // peel to 16B-aligned csrc index
    for (; i < e && (i & 3); i++)
        hacc(a0, A[(size_t)csrc[i] * 4 + lane]);
    // main: one nt int4 csrc load per 4 edges (same addr across lanes)
    for (; i + 4 <= e; i += 4) {
        int4 u = ntload_i4(csrc + i);
        half4 w0 = A[(size_t)u.x * 4 + lane];
        half4 w1 = A[(size_t)u.y * 4 + lane];
        half4 w2 = A[(size_t)u.z * 4 + lane];
        half4 w3 = A[(size_t)u.w * 4 + lane];
        hacc(a0, w0); hacc(a1, w1); hacc(a0, w2); hacc(a1, w3);
    }
    for (; i < e; i++) hacc(a0, A[(size_t)csrc[i] * 4 + lane]);
    a0.x += a1.x; a0.y += a1.y; a0.z += a1.z; a0.w += a1.w;

    float nv = nrm[v];
    size_t o = (size_t)v * 4 + lane;
    float4 hv = ntload_f4(tele + o * 4);
    float4 r;
    r.x = (1.0f - ALPHA) * a0.x * nv + ALPHA * hv.x;
    r.y = (1.0f - ALPHA) * a0.y * nv + ALPHA * hv.y;
    r.z = (1.0f - ALPHA) * a0.z * nv + ALPHA * hv.z;
    r.w = (1.0f - ALPHA) * a0.w * nv + ALPHA * hv.w;

    if (MODE == 0) {
        half4 w;
        w.a = __floats2half2_rn(r.x * nv, r.y * nv);
        w.b = __floats2half2_rn(r.z * nv, r.w * nv);
        ntstore_u64(&outp[o], *(unsigned long long*)&w);
    } else if (MODE == 1) {
        float4 b = b2v[lane];
        float4 x;
        x.x = eluf(r.x + b.x); x.y = eluf(r.y + b.y);
        x.z = eluf(r.z + b.z); x.w = eluf(r.w + b.w);
        ntstore_f4(x0out + o * 4, x);
        half4 w;
        w.a = __floats2half2_rn(x.x * nv, x.y * nv);
        w.b = __floats2half2_rn(x.z * nv, x.w * nv);
        ntstore_u64(&outp[o], *(unsigned long long*)&w);
    } else {
        ntstore_f4(outf + o * 4,
                   make_float4(eluf(r.x), eluf(r.y), eluf(r.z), eluf(r.w)));
    }
}

// ---------------- launch ----------------

extern "C" void kernel_launch(void* const* d_in, const int* in_sizes, int n_in,
                              void* d_out, int out_size, void* d_ws, size_t ws_size,
                              hipStream_t stream)
{
    const float* features = (const float*)d_in[0];
    const int*   src      = (const int*)d_in[1];
    const int*   dst      = (const int*)d_in[2];
    const float* W1       = (const float*)d_in[3];
    const float* b1       = (const float*)d_in[4];
    const float* W2       = (const float*)d_in[5];
    const float* b2       = (const float*)d_in[6];
    float* out = (float*)d_out;

    const int n  = in_sizes[0] / IN_DIM;   // 100000
    const int nE = in_sizes[1];            // 1600000

    // ws layout (words):
    // f32: nrm[n] | z0[16n] | x0[16n] | Wc[4096] | bc[16]
    // f16: PH[16n] | QH[16n]
    // int: deg[n] | off[n+4] | cursor[n] | bsum[1024] | csrc[nE]
    float* ws   = (float*)d_ws;
    float* nrm  = ws;
    float* z0   = nrm + n;
    float* x0   = z0 + (size_t)CLS * n;
    float* Wc   = x0 + (size_t)CLS * n;
    float* bc   = Wc + CLS * IN_DIM;
    __half* PH  = (__half*)(bc + 16);
    __half* QH  = PH + (size_t)CLS * n;
    int*   deg    = (int*)(QH + (size_t)CLS * n);
    int*   off    = deg + n;
    int*   cursor = off + n + 4;
    int*   bsum   = cursor + n;
    int*   csrc   = bsum + 1024;           // word offset divisible by 4 -> 16B aligned

    const int B = 256;
    const int nb = (n + 1023) / 1024;
    const int nper = (n + 7) / 8;

    // ---- degree, norm, CSR offsets ----
    zero_int_kernel<<<(n + B - 1) / B, B, 0, stream>>>(deg, n);
    hist_kernel<<<(nE + B - 1) / B, B, 0, stream>>>(dst, deg, nE);
    norm_kernel<<<(n + B - 1) / B, B, 0, stream>>>(deg, nrm, n);
    scan1_kernel<<<nb, 256, 0, stream>>>(deg, bsum, n);
    scan2_kernel<<<1, 64, 0, stream>>>(bsum, off, nb, n);
    scan3_kernel<<<nb, 256, 0, stream>>>(deg, bsum, off, cursor, n);

    // ---- XCD-partitioned filtered fill ----
    fill8_kernel<<<2048, 256, 0, stream>>>(src, dst, cursor, csrc, nE, nper);

    // ---- combined fc ----
    wc_kernel<<<CLS, 256, 0, stream>>>(W1, W2, b1, Wc, bc);
    fcz_kernel<<<(n + BM - 1) / BM, 256, 0, stream>>>(features, Wc, bc, nrm, z0, PH, n);

    dim3 gblk(4, 64);
    int ggrid = (n + 63) / 64;

    // ---- propagation 1 (teleport z0); last step fuses +b2, ELU ----
    __half* pa = PH; __half* pb = QH;
    for (int k = 0; k < K_STEPS; k++) {
        if (k < K_STEPS - 1)
            gatherh_kernel<0><<<ggrid, gblk, 0, stream>>>(
                off, csrc, (const half4*)pa, z0, nrm,
                nullptr, (half4*)pb, nullptr, nullptr, n);
        else
            gatherh_kernel<1><<<ggrid, gblk, 0, stream>>>(
                off, csrc, (const half4*)pa, z0, nrm,
                (const float4*)b2, (half4*)pb, x0, nullptr, n);
        __half* t = pa; pa = pb; pb = t;
    }

    // ---- propagation 2 (teleport x0); last step fuses ELU -> out ----
    for (int k = 0; k < K_STEPS; k++) {
        if (k < K_STEPS - 1)
            gatherh_kernel<0><<<ggrid, gblk, 0, stream>>>(
                off, csrc, (const half4*)pa, x0, nrm,
                nullptr, (half4*)pb, nullptr, nullptr, n);
        else
            gatherh_kernel<2><<<ggrid, gblk, 0, stream>>>(
                off, csrc, (const half4*)pa, x0, nrm,
                nullptr, nullptr, nullptr, out, n);
        __half* t = pa; pa = pb; pb = t;
    }
}

// Round 12
// 554.904 us; speedup vs baseline: 1.1900x; 1.1900x over previous
//
#include <hip/hip_runtime.h>
#include <hip/hip_fp16.h>
#include <math.h>

#define IN_DIM 256
#define HID 48
#define CLS 16
#define K_STEPS 10
#define ALPHA 0.1f

// ---------------- utility ----------------

__global__ void zero_int_kernel(int* __restrict__ p, int n) {
    int i = blockIdx.x * blockDim.x + threadIdx.x;
    if (i < n) p[i] = 0;
}

__global__ void hist_kernel(const int* __restrict__ dst, int* __restrict__ deg, int nE) {
    int i = blockIdx.x * blockDim.x + threadIdx.x;
    if (i < nE) atomicAdd(&deg[dst[i]], 1);
}

__global__ void norm_kernel(const int* __restrict__ deg, float* __restrict__ nrm, int n) {
    int i = blockIdx.x * blockDim.x + threadIdx.x;
    if (i < n) nrm[i] = rsqrtf(fmaxf((float)deg[i], 1.0f));
}

// ---------------- exclusive scan over deg -> off, cursor ----------------

__global__ __launch_bounds__(256) void scan1_kernel(const int* __restrict__ deg,
                                                    int* __restrict__ bsum, int n) {
    __shared__ int ls[256];
    int t = threadIdx.x;
    int base = blockIdx.x * 1024 + t * 4;
    int s = 0;
    if (base + 3 < n) {
        int4 d = *(const int4*)(deg + base);
        s = d.x + d.y + d.z + d.w;
    } else {
        for (int i = 0; i < 4; i++) if (base + i < n) s += deg[base + i];
    }
    ls[t] = s; __syncthreads();
    for (int o = 128; o > 0; o >>= 1) {
        if (t < o) ls[t] += ls[t + o];
        __syncthreads();
    }
    if (t == 0) bsum[blockIdx.x] = ls[0];
}

__global__ void scan2_kernel(int* __restrict__ bsum, int* __restrict__ off, int nb, int n) {
    if (threadIdx.x == 0 && blockIdx.x == 0) {
        int run = 0;
        for (int i = 0; i < nb; i++) { int t = bsum[i]; bsum[i] = run; run += t; }
        off[n] = run;
    }
}

__global__ __launch_bounds__(256) void scan3_kernel(const int* __restrict__ deg,
                                                    const int* __restrict__ bsum,
                                                    int* __restrict__ off,
                                                    int* __restrict__ cursor, int n) {
    __shared__ int ts[256];
    int t = threadIdx.x;
    int base = blockIdx.x * 1024 + t * 4;
    int d0 = 0, d1 = 0, d2 = 0, d3 = 0;
    if (base + 3 < n) {
        int4 d = *(const int4*)(deg + base);
        d0 = d.x; d1 = d.y; d2 = d.z; d3 = d.w;
    } else {
        if (base     < n) d0 = deg[base];
        if (base + 1 < n) d1 = deg[base + 1];
        if (base + 2 < n) d2 = deg[base + 2];
        if (base + 3 < n) d3 = deg[base + 3];
    }
    int s = d0 + d1 + d2 + d3;
    ts[t] = s; __syncthreads();
    for (int o = 1; o < 256; o <<= 1) {
        int v = (t >= o) ? ts[t - o] : 0;
        __syncthreads();
        ts[t] += v;
        __syncthreads();
    }
    int ex = ts[t] - s + bsum[blockIdx.x];
    int p0 = ex, p1 = ex + d0, p2 = p1 + d1, p3 = p2 + d2;
    if (base     < n) { off[base]     = p0; cursor[base]     = p0; }
    if (base + 1 < n) { off[base + 1] = p1; cursor[base + 1] = p1; }
    if (base + 2 < n) { off[base + 2] = p2; cursor[base + 2] = p2; }
    if (base + 3 < n) { off[base + 3] = p3; cursor[base + 3] = p3; }
}

// ---------------- XCD-partitioned filtered CSR fill ----------------

__global__ __launch_bounds__(256) void fill8_kernel(
    const int* __restrict__ src, const int* __restrict__ dst,
    int* __restrict__ cursor, int* __restrict__ csrc, int nE, int nper)
{
    const int g  = blockIdx.x & 7;
    const int bi = blockIdx.x >> 3;
    const int nb = gridDim.x >> 3;
    const int lo = g * nper, hi = lo + nper;
    for (int i = bi * 256 + threadIdx.x; i < nE; i += nb * 256) {
        int d = dst[i];
        if (d >= lo && d < hi) {
            int p = atomicAdd(&cursor[d], 1);
            csrc[p] = src[i];
        }
    }
}

// ---------------- Wc = W2 @ W1 [16,256], bc = W2 @ b1 [16] ----------------

__global__ __launch_bounds__(256) void wc_kernel(
    const float* __restrict__ W1, const float* __restrict__ W2,
    const float* __restrict__ b1, float* __restrict__ Wc, float* __restrict__ bc)
{
    int c = blockIdx.x;
    int k = threadIdx.x;
    float acc = 0.0f;
    #pragma unroll
    for (int j = 0; j < HID; j++)
        acc = fmaf(W2[c * HID + j], W1[j * IN_DIM + k], acc);
    Wc[c * IN_DIM + k] = acc;
    if (k == 0) {
        float b = 0.0f;
        for (int j = 0; j < HID; j++) b = fmaf(W2[c * HID + j], b1[j], b);
        bc[c] = b;
    }
}

// ---------------- fused fc: z0 = X @ Wc^T + bc (f32); A = half(z0*nrm) ----------------

#define BM 128
#define BK 16
__global__ __launch_bounds__(256) void fcz_kernel(
    const float* __restrict__ X, const float* __restrict__ Wc,
    const float* __restrict__ bc, const float* __restrict__ nrm,
    float* __restrict__ z0, __half* __restrict__ A, int n)
{
    __shared__ float Xs[BK][BM + 1];
    __shared__ float Ws[BK][CLS];
    const int t = threadIdx.x;
    const int tx = t & 31;
    const int ty = t >> 5;
    const int mbase = blockIdx.x * BM;
    float acc[4][2] = {{0}};

    for (int k0 = 0; k0 < IN_DIM; k0 += BK) {
        #pragma unroll
        for (int c0 = 0; c0 < 2; c0++) {
            int c = t + c0 * 256;
            int m = c >> 2, kc = (c & 3) << 2;
            int gm = mbase + m;
            float4 xv = make_float4(0.f, 0.f, 0.f, 0.f);
            if (gm < n) xv = *(const float4*)(X + (size_t)gm * IN_DIM + k0 + kc);
            Xs[kc + 0][m] = xv.x; Xs[kc + 1][m] = xv.y;
            Xs[kc + 2][m] = xv.z; Xs[kc + 3][m] = xv.w;
        }
        if (t < 64) {
            int j = t >> 2, kc = (t & 3) << 2;
            float4 wv = *(const float4*)(Wc + (size_t)j * IN_DIM + k0 + kc);
            Ws[kc + 0][j] = wv.x; Ws[kc + 1][j] = wv.y;
            Ws[kc + 2][j] = wv.z; Ws[kc + 3][j] = wv.w;
        }
        __syncthreads();
        #pragma unroll
        for (int k = 0; k < BK; k++) {
            float a[4], b[2];
            #pragma unroll
            for (int im = 0; im < 4; im++) a[im] = Xs[k][tx + 32 * im];
            #pragma unroll
            for (int jn = 0; jn < 2; jn++) b[jn] = Ws[k][ty * 2 + jn];
            #pragma unroll
            for (int im = 0; im < 4; im++)
                #pragma unroll
                for (int jn = 0; jn < 2; jn++)
                    acc[im][jn] = fmaf(a[im], b[jn], acc[im][jn]);
        }
        __syncthreads();
    }

    #pragma unroll
    for (int im = 0; im < 4; im++) {
        int m = mbase + tx + 32 * im;
        if (m < n) {
            float nv = nrm[m];
            float r0 = acc[im][0] + bc[ty * 2 + 0];
            float r1 = acc[im][1] + bc[ty * 2 + 1];
            size_t idx = (size_t)m * CLS + ty * 2;
            z0[idx] = r0;
            z0[idx + 1] = r1;
            ((__half2*)A)[(size_t)m * 8 + ty] = __floats2half2_rn(r0 * nv, r1 * nv);
        }
    }
}

// ---------------- pull gather + fused combine (D=16, half storage) ----------------
// 4 lanes/node, 8B loads, all lanes of an instruction within one 32B row.
// csrc as int4 per 4 edges (broadcast across lanes). 8-edge unroll: two int4
// csrc loads issued upfront -> 8 independent row loads in flight (deeper MLP
// for the L3-miss fraction of A reads).
// MODE 0: outp = half(r*nrm); MODE 1: x = elu(r+b2), x0 = x, outp = half(x*nrm);
// MODE 2: outf = elu(r).

struct __align__(8) half4 { __half2 a, b; };

__device__ __forceinline__ void hacc(float4& acc, half4 w) {
    float2 lo = __half22float2(w.a);
    float2 hi = __half22float2(w.b);
    acc.x += lo.x; acc.y += lo.y; acc.z += hi.x; acc.w += hi.y;
}
__device__ __forceinline__ float eluf(float x) {
    return x > 0.0f ? x : expm1f(x);
}

template<int MODE>
__global__ __launch_bounds__(256) void gatherh_kernel(
    const int* __restrict__ off, const int* __restrict__ csrc,
    const half4* __restrict__ A, const float4* __restrict__ tele,
    const float* __restrict__ nrm, const float4* __restrict__ b2v,
    half4* __restrict__ outp, float4* __restrict__ x0out,
    float4* __restrict__ outf, int n)
{
    const int v = blockIdx.x * 64 + threadIdx.y;
    if (v >= n) return;
    const int lane = threadIdx.x;        // 0..3

    const int s = off[v], e = off[v + 1];
    float4 a0 = make_float4(0.f, 0.f, 0.f, 0.f), a1 = a0;
    int i = s;
    // peel to 16B-aligned csrc index
    for (; i < e && (i & 3); i++)
        hacc(a0, A[(size_t)csrc[i] * 4 + lane]);
    // main: 8 edges per iteration, 2 int4 csrc loads, 8 row loads in flight
    for (; i + 8 <= e; i += 8) {
        int4 u = *(const int4*)(csrc + i);
        int4 q = *(const int4*)(csrc + i + 4);
        half4 w0 = A[(size_t)u.x * 4 + lane];
        half4 w1 = A[(size_t)u.y * 4 + lane];
        half4 w2 = A[(size_t)u.z * 4 + lane];
        half4 w3 = A[(size_t)u.w * 4 + lane];
        half4 w4 = A[(size_t)q.x * 4 + lane];
        half4 w5 = A[(size_t)q.y * 4 + lane];
        half4 w6 = A[(size_t)q.z * 4 + lane];
        half4 w7 = A[(size_t)q.w * 4 + lane];
        hacc(a0, w0); hacc(a1, w1); hacc(a0, w2); hacc(a1, w3);
        hacc(a0, w4); hacc(a1, w5); hacc(a0, w6); hacc(a1, w7);
    }
    // 4-edge step
    for (; i + 4 <= e; i += 4) {
        int4 u = *(const int4*)(csrc + i);
        half4 w0 = A[(size_t)u.x * 4 + lane];
        half4 w1 = A[(size_t)u.y * 4 + lane];
        half4 w2 = A[(size_t)u.z * 4 + lane];
        half4 w3 = A[(size_t)u.w * 4 + lane];
        hacc(a0, w0); hacc(a1, w1); hacc(a0, w2); hacc(a1, w3);
    }
    for (; i < e; i++) hacc(a0, A[(size_t)csrc[i] * 4 + lane]);
    a0.x += a1.x; a0.y += a1.y; a0.z += a1.z; a0.w += a1.w;

    float nv = nrm[v];
    size_t o = (size_t)v * 4 + lane;
    float4 hv = tele[o];
    float4 r;
    r.x = (1.0f - ALPHA) * a0.x * nv + ALPHA * hv.x;
    r.y = (1.0f - ALPHA) * a0.y * nv + ALPHA * hv.y;
    r.z = (1.0f - ALPHA) * a0.z * nv + ALPHA * hv.z;
    r.w = (1.0f - ALPHA) * a0.w * nv + ALPHA * hv.w;

    if (MODE == 0) {
        half4 w;
        w.a = __floats2half2_rn(r.x * nv, r.y * nv);
        w.b = __floats2half2_rn(r.z * nv, r.w * nv);
        outp[o] = w;
    } else if (MODE == 1) {
        float4 b = b2v[lane];
        float4 x;
        x.x = eluf(r.x + b.x); x.y = eluf(r.y + b.y);
        x.z = eluf(r.z + b.z); x.w = eluf(r.w + b.w);
        x0out[o] = x;
        half4 w;
        w.a = __floats2half2_rn(x.x * nv, x.y * nv);
        w.b = __floats2half2_rn(x.z * nv, x.w * nv);
        outp[o] = w;
    } else {
        outf[o] = make_float4(eluf(r.x), eluf(r.y), eluf(r.z), eluf(r.w));
    }
}

// ---------------- launch ----------------

extern "C" void kernel_launch(void* const* d_in, const int* in_sizes, int n_in,
                              void* d_out, int out_size, void* d_ws, size_t ws_size,
                              hipStream_t stream)
{
    const float* features = (const float*)d_in[0];
    const int*   src      = (const int*)d_in[1];
    const int*   dst      = (const int*)d_in[2];
    const float* W1       = (const float*)d_in[3];
    const float* b1       = (const float*)d_in[4];
    const float* W2       = (const float*)d_in[5];
    const float* b2       = (const float*)d_in[6];
    float* out = (float*)d_out;

    const int n  = in_sizes[0] / IN_DIM;   // 100000
    const int nE = in_sizes[1];            // 1600000

    // ws layout (words):
    // f32: nrm[n] | z0[16n] | x0[16n] | Wc[4096] | bc[16]
    // f16: PH[16n] | QH[16n]
    // int: deg[n] | off[n+4] | cursor[n] | bsum[1024] | csrc[nE]
    float* ws   = (float*)d_ws;
    float* nrm  = ws;
    float* z0   = nrm + n;
    float* x0   = z0 + (size_t)CLS * n;
    float* Wc   = x0 + (size_t)CLS * n;
    float* bc   = Wc + CLS * IN_DIM;
    __half* PH  = (__half*)(bc + 16);
    __half* QH  = PH + (size_t)CLS * n;
    int*   deg    = (int*)(QH + (size_t)CLS * n);
    int*   off    = deg + n;
    int*   cursor = off + n + 4;
    int*   bsum   = cursor + n;
    int*   csrc   = bsum + 1024;           // word offset divisible by 4 -> 16B aligned

    const int B = 256;
    const int nb = (n + 1023) / 1024;
    const int nper = (n + 7) / 8;

    // ---- degree, norm, CSR offsets ----
    zero_int_kernel<<<(n + B - 1) / B, B, 0, stream>>>(deg, n);
    hist_kernel<<<(nE + B - 1) / B, B, 0, stream>>>(dst, deg, nE);
    norm_kernel<<<(n + B - 1) / B, B, 0, stream>>>(deg, nrm, n);
    scan1_kernel<<<nb, 256, 0, stream>>>(deg, bsum, n);
    scan2_kernel<<<1, 64, 0, stream>>>(bsum, off, nb, n);
    scan3_kernel<<<nb, 256, 0, stream>>>(deg, bsum, off, cursor, n);

    // ---- XCD-partitioned filtered fill ----
    fill8_kernel<<<2048, 256, 0, stream>>>(src, dst, cursor, csrc, nE, nper);

    // ---- combined fc ----
    wc_kernel<<<CLS, 256, 0, stream>>>(W1, W2, b1, Wc, bc);
    fcz_kernel<<<(n + BM - 1) / BM, 256, 0, stream>>>(features, Wc, bc, nrm, z0, PH, n);

    dim3 gblk(4, 64);
    int ggrid = (n + 63) / 64;

    // ---- propagation 1 (teleport z0); last step fuses +b2, ELU ----
    __half* pa = PH; __half* pb = QH;
    for (int k = 0; k < K_STEPS; k++) {
        if (k < K_STEPS - 1)
            gatherh_kernel<0><<<ggrid, gblk, 0, stream>>>(
                off, csrc, (const half4*)pa, (const float4*)z0, nrm,
                nullptr, (half4*)pb, nullptr, nullptr, n);
        else
            gatherh_kernel<1><<<ggrid, gblk, 0, stream>>>(
                off, csrc, (const half4*)pa, (const float4*)z0, nrm,
                (const float4*)b2, (half4*)pb, (float4*)x0, nullptr, n);
        __half* t = pa; pa = pb; pb = t;
    }

    // ---- propagation 2 (teleport x0); last step fuses ELU -> out ----
    for (int k = 0; k < K_STEPS; k++) {
        if (k < K_STEPS - 1)
            gatherh_kernel<0><<<ggrid, gblk, 0, stream>>>(
                off, csrc, (const half4*)pa, (const float4*)x0, nrm,
                nullptr, (half4*)pb, nullptr, nullptr, n);
        else
            gatherh_kernel<2><<<ggrid, gblk, 0, stream>>>(
                off, csrc, (const half4*)pa, (const float4*)x0, nrm,
                nullptr, nullptr, nullptr, (float4*)out, n);
        __half* t = pa; pa = pb; pb = t;
    }
}